// Round 1
// baseline (2569.464 us; speedup 1.0000x reference)
//
#include <hip/hip_runtime.h>
#include <math.h>

// Problem constants
#define BN 131072
#define DD 256
#define NE 4

// ---------------- workspace layout (d_ws) ----------------
// [0,32)            double psum[4]     -- sum of top-prob per expert
// [32,48)           int    listpos[4]  -- per-expert row count / append cursor
// [48,64)           float  avg[4]      -- psum/count
// [64, 64+4*BN*4)   int    lists[4][BN]-- compacted row indices per expert
// total ~2 MiB + 64 B

// ============================================================
// init: zero the atomics (ws is re-poisoned 0xAA before every call)
// ============================================================
__global__ void k_init(int* __restrict__ listpos, double* __restrict__ psum) {
  int t = threadIdx.x;
  if (t < NE) { listpos[t] = 0; psum[t] = 0.0; }
}

// ============================================================
// gating: fp64 logits (match numpy-f64 top-1 decisions), softmax,
// top-1, warp-aggregated compaction append + per-expert prob sums.
// Thread-per-row; grid = BN/256 blocks x 256 threads.
// ============================================================
#define GACC(xv, wv)                                \
  l0 = fma((double)(xv), (double)(wv).x, l0);       \
  l1 = fma((double)(xv), (double)(wv).y, l1);       \
  l2 = fma((double)(xv), (double)(wv).z, l2);       \
  l3 = fma((double)(xv), (double)(wv).w, l3);

__global__ __launch_bounds__(256) void k_gate(
    const float* __restrict__ zg, const float* __restrict__ zn,
    const float* __restrict__ gW, const float* __restrict__ gb,
    int* __restrict__ listpos, double* __restrict__ psum,
    int* __restrict__ lists) {
  int row = blockIdx.x * 256 + threadIdx.x;
  int lane = threadIdx.x & 63;
  const float* zgr = zg + (size_t)row * DD;
  const float* znr = zn + (size_t)row * DD;
  double l0 = (double)gb[0], l1 = (double)gb[1], l2 = (double)gb[2], l3 = (double)gb[3];
  for (int i = 0; i < DD; i += 4) {
    float4 a4 = *(const float4*)(zgr + i);
    float4 b4 = *(const float4*)(znr + i);
    float4 wa0 = *(const float4*)(gW + (i + 0) * 4);
    float4 wa1 = *(const float4*)(gW + (i + 1) * 4);
    float4 wa2 = *(const float4*)(gW + (i + 2) * 4);
    float4 wa3 = *(const float4*)(gW + (i + 3) * 4);
    float4 wb0 = *(const float4*)(gW + (DD + i + 0) * 4);
    float4 wb1 = *(const float4*)(gW + (DD + i + 1) * 4);
    float4 wb2 = *(const float4*)(gW + (DD + i + 2) * 4);
    float4 wb3 = *(const float4*)(gW + (DD + i + 3) * 4);
    GACC(a4.x, wa0) GACC(a4.y, wa1) GACC(a4.z, wa2) GACC(a4.w, wa3)
    GACC(b4.x, wb0) GACC(b4.y, wb1) GACC(b4.z, wb2) GACC(b4.w, wb3)
  }
  // argmax, first index wins on ties (strict >)
  int e = 0; double lm = l0;
  if (l1 > lm) { lm = l1; e = 1; }
  if (l2 > lm) { lm = l2; e = 2; }
  if (l3 > lm) { lm = l3; e = 3; }
  double s = exp(l0 - lm) + exp(l1 - lm) + exp(l2 - lm) + exp(l3 - lm);
  double p = 1.0 / s;  // top softmax prob: exp(lm-lm)/s

  #pragma unroll
  for (int ee = 0; ee < NE; ++ee) {
    bool mine = (e == ee);
    unsigned long long mask = __ballot(mine);
    int cnt = __popcll(mask);
    // wave-sum of selected probs -> lane 0
    double pv = mine ? p : 0.0;
    #pragma unroll
    for (int off = 32; off; off >>= 1) pv += __shfl_down(pv, off);
    if (cnt) {
      int leader = __ffsll((unsigned long long)mask) - 1;
      int basev = 0;
      if (lane == leader) basev = atomicAdd(&listpos[ee], cnt);
      basev = __shfl(basev, leader);
      if (mine) {
        int rank = __popcll(mask & ((1ull << lane) - 1ull));
        lists[(size_t)ee * BN + basev + rank] = row;
      }
      if (lane == 0) atomicAdd(&psum[ee], pv);
    }
  }
}

// ============================================================
// finalize: avg[e] = psum/cnt, aux_loss -> d_out[BN*DD]
// ============================================================
__global__ void k_finalize(const int* __restrict__ listpos,
                           const double* __restrict__ psum,
                           float* __restrict__ avg, float* __restrict__ aux_out) {
  if (threadIdx.x == 0) {
    double aux = 0.0;
    for (int ee = 0; ee < NE; ++ee) {
      int c = listpos[ee];
      avg[ee] = (c > 0) ? (float)(psum[ee] / (double)c) : 0.0f;
      double u = (double)c / (double)BN;
      aux += u * u;
    }
    *aux_out = (float)(aux * (double)NE);
  }
}

// ============================================================
// Shared tiled-GEMM core. Block = 256 threads: tc = tid&63 (4 cols),
// tr = tid>>6 (4 rows). Computes acc[4][4] += A[16 x K] @ W[K x 256]
// for rows tr*4..tr*4+3, cols tc*4..tc*4+3. A in LDS (row stride K,
// broadcast reads), W global float4 (coalesced, L1/L2-hot).
// ============================================================
#define FMA4(xc, wv, r)                              \
  acc[r][0] = fmaf((xc), (wv).x, acc[r][0]);         \
  acc[r][1] = fmaf((xc), (wv).y, acc[r][1]);         \
  acc[r][2] = fmaf((xc), (wv).z, acc[r][2]);         \
  acc[r][3] = fmaf((xc), (wv).w, acc[r][3]);

template <int K>
__device__ __forceinline__ void tile_gemm_acc(const float* __restrict__ A,
                                              const float* __restrict__ W,
                                              int tc, int tr, float acc[4][4]) {
  const float* wp = W + tc * 4;
  const float* ap = A + (tr * 4) * K;
  #pragma unroll 2
  for (int i = 0; i < K; i += 4) {
    float4 w0 = *(const float4*)(wp + (i + 0) * DD);
    float4 w1 = *(const float4*)(wp + (i + 1) * DD);
    float4 w2 = *(const float4*)(wp + (i + 2) * DD);
    float4 w3 = *(const float4*)(wp + (i + 3) * DD);
    #pragma unroll
    for (int r = 0; r < 4; ++r) {
      float4 x = *(const float4*)(ap + r * K + i);
      FMA4(x.x, w0, r) FMA4(x.y, w1, r) FMA4(x.z, w2, r) FMA4(x.w, w3, r)
    }
  }
}

// epilogue: bias (+ optional relu) -> LDS Dst[16][256]
template <int RELU>
__device__ __forceinline__ void store_tile_lds(float acc[4][4],
                                               const float* __restrict__ bias,
                                               float* __restrict__ Dst, int tc, int tr) {
  float4 b = *(const float4*)(bias + tc * 4);
  #pragma unroll
  for (int r = 0; r < 4; ++r) {
    float v0 = acc[r][0] + b.x, v1 = acc[r][1] + b.y;
    float v2 = acc[r][2] + b.z, v3 = acc[r][3] + b.w;
    if (RELU) {
      v0 = fmaxf(v0, 0.f); v1 = fmaxf(v1, 0.f);
      v2 = fmaxf(v2, 0.f); v3 = fmaxf(v3, 0.f);
    }
    *(float4*)(Dst + (tr * 4 + r) * DD + tc * 4) = make_float4(v0, v1, v2, v3);
  }
}

// epilogue: bias + scale -> global rows rl[]
__device__ __forceinline__ void store_tile_out(float acc[4][4],
                                               const float* __restrict__ bias,
                                               float scale, const int* __restrict__ rl,
                                               float* __restrict__ out, int tc, int tr) {
  float4 b = *(const float4*)(bias + tc * 4);
  #pragma unroll
  for (int r = 0; r < 4; ++r) {
    int row = rl[tr * 4 + r];
    if (row < 0) continue;
    float4 o;
    o.x = (acc[r][0] + b.x) * scale;
    o.y = (acc[r][1] + b.y) * scale;
    o.z = (acc[r][2] + b.z) * scale;
    o.w = (acc[r][3] + b.w) * scale;
    *(float4*)(out + (size_t)row * DD + tc * 4) = o;
  }
}

// ============================================================
// Expert 0: concat   h = relu([zg,zn] @ W1 + b1); out = h @ W2 + b2
// ============================================================
__global__ __launch_bounds__(256) void k_concat(
    const float* __restrict__ zg, const float* __restrict__ zn,
    const float* __restrict__ W1, const float* __restrict__ b1,
    const float* __restrict__ W2, const float* __restrict__ b2,
    const int* __restrict__ listpos, const int* __restrict__ lists,
    const float* __restrict__ avgp, float* __restrict__ out) {
  __shared__ float xs[16 * 512];
  __shared__ float hs[16 * 256];
  __shared__ int rl[16];
  int n = listpos[0];
  const int* lst = lists + 0 * (size_t)BN;
  float scale = avgp[0];
  int tid = threadIdx.x, tc = tid & 63, tr = tid >> 6;

  for (int tile = blockIdx.x; tile * 16 < n; tile += gridDim.x) {
    int base = tile * 16;
    __syncthreads();
    if (tid < 16) rl[tid] = (base + tid < n) ? lst[base + tid] : -1;
    __syncthreads();
    #pragma unroll
    for (int j = 0; j < 8; ++j) {
      int t = tid + j * 256;
      int row = t >> 7, off = t & 127;
      int r = rl[row];
      float4 v = make_float4(0.f, 0.f, 0.f, 0.f);
      if (r >= 0)
        v = (off < 64) ? *(const float4*)(zg + (size_t)r * DD + off * 4)
                       : *(const float4*)(zn + (size_t)r * DD + (off - 64) * 4);
      *(float4*)(xs + row * 512 + off * 4) = v;
    }
    __syncthreads();
    {
      float acc[4][4] = {};
      tile_gemm_acc<512>(xs, W1, tc, tr, acc);
      store_tile_lds<1>(acc, b1, hs, tc, tr);
    }
    __syncthreads();
    {
      float acc[4][4] = {};
      tile_gemm_acc<256>(hs, W2, tc, tr, acc);
      store_tile_out(acc, b2, scale, rl, out, tc, tr);
    }
  }
}

// ============================================================
// Expert 1: mul   h = relu((zg*zn) @ W1 + b1); out = h @ W2 + b2
// ============================================================
__global__ __launch_bounds__(256) void k_mul(
    const float* __restrict__ zg, const float* __restrict__ zn,
    const float* __restrict__ W1, const float* __restrict__ b1,
    const float* __restrict__ W2, const float* __restrict__ b2,
    const int* __restrict__ listpos, const int* __restrict__ lists,
    const float* __restrict__ avgp, float* __restrict__ out) {
  __shared__ float ps[16 * 256];
  __shared__ float hs[16 * 256];
  __shared__ int rl[16];
  int n = listpos[1];
  const int* lst = lists + 1 * (size_t)BN;
  float scale = avgp[1];
  int tid = threadIdx.x, tc = tid & 63, tr = tid >> 6;

  for (int tile = blockIdx.x; tile * 16 < n; tile += gridDim.x) {
    int base = tile * 16;
    __syncthreads();
    if (tid < 16) rl[tid] = (base + tid < n) ? lst[base + tid] : -1;
    __syncthreads();
    #pragma unroll
    for (int j = 0; j < 4; ++j) {
      int t = tid + j * 256;
      int row = t >> 6, off = t & 63;
      int r = rl[row];
      float4 v = make_float4(0.f, 0.f, 0.f, 0.f);
      if (r >= 0) {
        float4 g = *(const float4*)(zg + (size_t)r * DD + off * 4);
        float4 h = *(const float4*)(zn + (size_t)r * DD + off * 4);
        v = make_float4(g.x * h.x, g.y * h.y, g.z * h.z, g.w * h.w);
      }
      *(float4*)(ps + row * 256 + off * 4) = v;
    }
    __syncthreads();
    {
      float acc[4][4] = {};
      tile_gemm_acc<256>(ps, W1, tc, tr, acc);
      store_tile_lds<1>(acc, b1, hs, tc, tr);
    }
    __syncthreads();
    {
      float acc[4][4] = {};
      tile_gemm_acc<256>(hs, W2, tc, tr, acc);
      store_tile_out(acc, b2, scale, rl, out, tc, tr);
    }
  }
}

// ============================================================
// Expert 3: wsum   alpha = sigmoid([zg,zn] @ Wa + ba);
//                  h = alpha*zg + (1-alpha)*zn; out = h @ Wo + bo
// ============================================================
__global__ __launch_bounds__(256) void k_wsum(
    const float* __restrict__ zg, const float* __restrict__ zn,
    const float* __restrict__ Wa, const float* __restrict__ ba,
    const float* __restrict__ Wo, const float* __restrict__ bo,
    const int* __restrict__ listpos, const int* __restrict__ lists,
    const float* __restrict__ avgp, float* __restrict__ out) {
  __shared__ float xs[16 * 512];
  __shared__ float hs[16 * 256];
  __shared__ int rl[16];
  int n = listpos[3];
  const int* lst = lists + 3 * (size_t)BN;
  float scale = avgp[3];
  int tid = threadIdx.x, tc = tid & 63, tr = tid >> 6;

  for (int tile = blockIdx.x; tile * 16 < n; tile += gridDim.x) {
    int base = tile * 16;
    __syncthreads();
    if (tid < 16) rl[tid] = (base + tid < n) ? lst[base + tid] : -1;
    __syncthreads();
    #pragma unroll
    for (int j = 0; j < 8; ++j) {
      int t = tid + j * 256;
      int row = t >> 7, off = t & 127;
      int r = rl[row];
      float4 v = make_float4(0.f, 0.f, 0.f, 0.f);
      if (r >= 0)
        v = (off < 64) ? *(const float4*)(zg + (size_t)r * DD + off * 4)
                       : *(const float4*)(zn + (size_t)r * DD + (off - 64) * 4);
      *(float4*)(xs + row * 512 + off * 4) = v;
    }
    __syncthreads();
    {
      float acc[4][4] = {};
      tile_gemm_acc<512>(xs, Wa, tc, tr, acc);
      float4 b = *(const float4*)(ba + tc * 4);
      #pragma unroll
      for (int r = 0; r < 4; ++r) {
        int vr = tr * 4 + r;
        float4 xg = *(const float4*)(xs + vr * 512 + tc * 4);
        float4 xn = *(const float4*)(xs + vr * 512 + 256 + tc * 4);
        float a0 = 1.f / (1.f + expf(-(acc[r][0] + b.x)));
        float a1 = 1.f / (1.f + expf(-(acc[r][1] + b.y)));
        float a2 = 1.f / (1.f + expf(-(acc[r][2] + b.z)));
        float a3 = 1.f / (1.f + expf(-(acc[r][3] + b.w)));
        float4 h;
        h.x = a0 * xg.x + (1.f - a0) * xn.x;
        h.y = a1 * xg.y + (1.f - a1) * xn.y;
        h.z = a2 * xg.z + (1.f - a2) * xn.z;
        h.w = a3 * xg.w + (1.f - a3) * xn.w;
        *(float4*)(hs + vr * 256 + tc * 4) = h;
      }
    }
    __syncthreads();
    {
      float acc[4][4] = {};
      tile_gemm_acc<256>(hs, Wo, tc, tr, acc);
      store_tile_out(acc, bo, scale, rl, out, tc, tr);
    }
  }
}

// ============================================================
// Expert 2: attention. R=8 rows/block, 16 "vrows" (row,pos).
// ============================================================
__global__ __launch_bounds__(256) void k_attn(
    const float* __restrict__ zg, const float* __restrict__ zn,
    const float* __restrict__ Wq, const float* __restrict__ bq,
    const float* __restrict__ Wk, const float* __restrict__ bk,
    const float* __restrict__ Wv, const float* __restrict__ bv,
    const float* __restrict__ Wo, const float* __restrict__ bo,
    const float* __restrict__ Wfc, const float* __restrict__ bfc,
    const int* __restrict__ listpos, const int* __restrict__ lists,
    const float* __restrict__ avgp, float* __restrict__ out) {
  __shared__ float xs[8 * 512];   // vrow-major: xs[v*256 + j], v = r*2+pos
  __shared__ float QB[16 * 256];
  __shared__ float KB[16 * 256];
  __shared__ float VB[16 * 256];
  __shared__ float AW[8 * 4 * 2 * 2];  // [r][h][qp][kp]
  __shared__ float MO[8 * 256];
  __shared__ int rl[8];
  int n = listpos[2];
  const int* lst = lists + 2 * (size_t)BN;
  float scale = avgp[2];
  int tid = threadIdx.x, tc = tid & 63, tr = tid >> 6;

  for (int tile = blockIdx.x; tile * 8 < n; tile += gridDim.x) {
    int base = tile * 8;
    __syncthreads();
    if (tid < 8) rl[tid] = (base + tid < n) ? lst[base + tid] : -1;
    __syncthreads();
    // load zs: vrow v=r*2+0 is zg row, v=r*2+1 is zn row
    #pragma unroll
    for (int j = 0; j < 4; ++j) {
      int t = tid + j * 256;          // 0..1023 float4s
      int row = t >> 7, off = t & 127;
      int r = rl[row];
      float4 v = make_float4(0.f, 0.f, 0.f, 0.f);
      if (r >= 0)
        v = (off < 64) ? *(const float4*)(zg + (size_t)r * DD + off * 4)
                       : *(const float4*)(zn + (size_t)r * DD + (off - 64) * 4);
      *(float4*)(xs + row * 512 + off * 4) = v;
    }
    __syncthreads();
    // Q, K, V (each 16 vrows x 256, K=256)
    {
      float acc[4][4] = {};
      tile_gemm_acc<256>(xs, Wq, tc, tr, acc);
      store_tile_lds<0>(acc, bq, QB, tc, tr);
    }
    {
      float acc[4][4] = {};
      tile_gemm_acc<256>(xs, Wk, tc, tr, acc);
      store_tile_lds<0>(acc, bk, KB, tc, tr);
    }
    {
      float acc[4][4] = {};
      tile_gemm_acc<256>(xs, Wv, tc, tr, acc);
      store_tile_lds<0>(acc, bv, VB, tc, tr);
    }
    __syncthreads();
    // attention weights: 8 rows x 4 heads x 2 qpos, both kpos dots
    if (tid < 64) {
      int r = tid >> 3, h = (tid >> 1) & 3, qp = tid & 1;
      const float* q = QB + (r * 2 + qp) * 256 + h * 64;
      const float* k0 = KB + (r * 2 + 0) * 256 + h * 64;
      const float* k1 = KB + (r * 2 + 1) * 256 + h * 64;
      float s0 = 0.f, s1 = 0.f;
      for (int t = 0; t < 64; ++t) {
        int d = (t + tid) & 63;  // stagger to avoid bank conflicts
        float qq = q[d];
        s0 += qq * k0[d];
        s1 += qq * k1[d];
      }
      s0 *= 0.125f; s1 *= 0.125f;   // 1/sqrt(64)
      float m = fmaxf(s0, s1);
      float e0 = expf(s0 - m), e1 = expf(s1 - m);
      float inv = 1.f / (e0 + e1);
      AW[((r * 4 + h) * 2 + qp) * 2 + 0] = e0 * inv;
      AW[((r * 4 + h) * 2 + qp) * 2 + 1] = e1 * inv;
    }
    __syncthreads();
    // o = a @ v  -> overwrite QB
    #pragma unroll
    for (int j2 = 0; j2 < 16; ++j2) {
      int idx = tid + j2 * 256;       // 16*256
      int v = idx >> 8, j = idx & 255;
      int r = v >> 1, qp = v & 1, h = j >> 6;
      float a0 = AW[((r * 4 + h) * 2 + qp) * 2 + 0];
      float a1 = AW[((r * 4 + h) * 2 + qp) * 2 + 1];
      QB[idx] = a0 * VB[(r * 2 + 0) * 256 + j] + a1 * VB[(r * 2 + 1) * 256 + j];
    }
    __syncthreads();
    // oo = o @ Wo + bo -> KB
    {
      float acc[4][4] = {};
      tile_gemm_acc<256>(QB, Wo, tc, tr, acc);
      store_tile_lds<0>(acc, bo, KB, tc, tr);
    }
    __syncthreads();
    // mean over pos -> MO[8][256]
    #pragma unroll
    for (int j2 = 0; j2 < 8; ++j2) {
      int idx = tid + j2 * 256;       // 8*256
      int r = idx >> 8, j = idx & 255;
      MO[idx] = 0.5f * (KB[(r * 2 + 0) * 256 + j] + KB[(r * 2 + 1) * 256 + j]);
    }
    __syncthreads();
    // out = MO @ Wfc + bfc (8 rows): tr handles rows tr*2, tr*2+1
    {
      float acc[2][4] = {};
      const float* wp = Wfc + tc * 4;
      #pragma unroll 2
      for (int i = 0; i < 256; i += 4) {
        float4 w0 = *(const float4*)(wp + (i + 0) * DD);
        float4 w1 = *(const float4*)(wp + (i + 1) * DD);
        float4 w2 = *(const float4*)(wp + (i + 2) * DD);
        float4 w3 = *(const float4*)(wp + (i + 3) * DD);
        #pragma unroll
        for (int r = 0; r < 2; ++r) {
          float4 x = *(const float4*)(MO + (tr * 2 + r) * 256 + i);
          FMA4(x.x, w0, r) FMA4(x.y, w1, r) FMA4(x.z, w2, r) FMA4(x.w, w3, r)
        }
      }
      float4 b = *(const float4*)(bfc + tc * 4);
      #pragma unroll
      for (int r = 0; r < 2; ++r) {
        int row = rl[tr * 2 + r];
        if (row < 0) continue;
        float4 o;
        o.x = (acc[r][0] + b.x) * scale;
        o.y = (acc[r][1] + b.y) * scale;
        o.z = (acc[r][2] + b.z) * scale;
        o.w = (acc[r][3] + b.w) * scale;
        *(float4*)(out + (size_t)row * DD + tc * 4) = o;
      }
    }
  }
}

// ============================================================
// launch
// ============================================================
extern "C" void kernel_launch(void* const* d_in, const int* in_sizes, int n_in,
                              void* d_out, int out_size, void* d_ws, size_t ws_size,
                              hipStream_t stream) {
  const float* zg   = (const float*)d_in[0];
  const float* zn   = (const float*)d_in[1];
  const float* gW   = (const float*)d_in[2];
  const float* gb   = (const float*)d_in[3];
  const float* cW1  = (const float*)d_in[4];
  const float* cb1  = (const float*)d_in[5];
  const float* cW2  = (const float*)d_in[6];
  const float* cb2  = (const float*)d_in[7];
  const float* mW1  = (const float*)d_in[8];
  const float* mb1  = (const float*)d_in[9];
  const float* mW2  = (const float*)d_in[10];
  const float* mb2  = (const float*)d_in[11];
  const float* aWq  = (const float*)d_in[12];
  const float* abq  = (const float*)d_in[13];
  const float* aWk  = (const float*)d_in[14];
  const float* abk  = (const float*)d_in[15];
  const float* aWv  = (const float*)d_in[16];
  const float* abv  = (const float*)d_in[17];
  const float* aWo  = (const float*)d_in[18];
  const float* abo  = (const float*)d_in[19];
  const float* aWfc = (const float*)d_in[20];
  const float* abfc = (const float*)d_in[21];
  const float* wWa  = (const float*)d_in[22];
  const float* wba  = (const float*)d_in[23];
  const float* wWo  = (const float*)d_in[24];
  const float* wbo  = (const float*)d_in[25];
  float* out = (float*)d_out;

  char* ws = (char*)d_ws;
  double* psum  = (double*)ws;
  int* listpos  = (int*)(ws + 32);
  float* avg    = (float*)(ws + 48);
  int* lists    = (int*)(ws + 64);

  hipLaunchKernelGGL(k_init, dim3(1), dim3(64), 0, stream, listpos, psum);
  hipLaunchKernelGGL(k_gate, dim3(BN / 256), dim3(256), 0, stream,
                     zg, zn, gW, gb, listpos, psum, lists);
  hipLaunchKernelGGL(k_finalize, dim3(1), dim3(64), 0, stream,
                     listpos, psum, avg, out + (size_t)BN * DD);
  hipLaunchKernelGGL(k_concat, dim3(2048), dim3(256), 0, stream,
                     zg, zn, cW1, cb1, cW2, cb2, listpos, lists, avg, out);
  hipLaunchKernelGGL(k_mul, dim3(2048), dim3(256), 0, stream,
                     zg, zn, mW1, mb1, mW2, mb2, listpos, lists, avg, out);
  hipLaunchKernelGGL(k_attn, dim3(4096), dim3(256), 0, stream,
                     zg, zn, aWq, abq, aWk, abk, aWv, abv, aWo, abo, aWfc, abfc,
                     listpos, lists, avg, out);
  hipLaunchKernelGGL(k_wsum, dim3(2048), dim3(256), 0, stream,
                     zg, zn, wWa, wba, wWo, wbo, listpos, lists, avg, out);
}

// Round 2
// 1512.435 us; speedup vs baseline: 1.6989x; 1.6989x over previous
//
#include <hip/hip_runtime.h>
#include <math.h>

#define BN 131072
#define DD 256
#define NE 4

typedef unsigned short u16;
typedef __bf16 bf16x8 __attribute__((ext_vector_type(8)));
typedef float f32x4 __attribute__((ext_vector_type(4)));

__device__ __forceinline__ u16 f2bf(float f) {
  union { float f; unsigned int u; } v; v.f = f;
  unsigned int u = v.u;
  unsigned int r = (u + 0x7FFFu + ((u >> 16) & 1u)) >> 16;
  return (u16)r;
}
__device__ __forceinline__ float bf2f(u16 x) {
  union { unsigned int u; float f; } v; v.u = ((unsigned int)x) << 16; return v.f;
}

// ---------------- workspace layout (d_ws) ----------------
// [0,32)    double psum[4]
// [32,48)   int    listpos[4]
// [48,64)   float  avg[4]
// [64, 64+4*BN*4)  int lists[4][BN]
// [2097216, +1703936) u16 swizzled bf16 weights
#define WS_SWZ_OFF 2097216

// bf16 weight element offsets (in elements) within swizzle area
#define OFF_CW1  0
#define OFF_CW2  131072
#define OFF_MW1  196608
#define OFF_MW2  262144
#define OFF_AWQ  327680
#define OFF_AWK  393216
#define OFF_AWV  458752
#define OFF_AWO  524288
#define OFF_AWFC 589824
#define OFF_WWA  655360
#define OFF_WWO  786432
#define SWZ_TOTAL_GROUPS 106496   // 851968/8

// ============================================================
// init
// ============================================================
__global__ void k_init(int* __restrict__ listpos, double* __restrict__ psum) {
  int t = threadIdx.x;
  if (t < NE) { listpos[t] = 0; psum[t] = 0.0; }
}

// ============================================================
// weight swizzle: fp32 W[K x 256] -> bf16 in B-fragment order:
// dst[((ct*KS + ks)*64 + lane)*8 + j] = W[ks*32 + (lane>>4)*8 + j][ct*16 + (lane&15)]
// ============================================================
struct SwzArgs {
  const float* src[11];
  int KS[11];       // K/32
  int lks[11];      // log2(KS)
  int dstoff[11];   // element offset in swizzle area
  int gbase[11];    // cumulative group base
};

__global__ __launch_bounds__(256) void k_swz(SwzArgs a, u16* __restrict__ dst) {
  int g = blockIdx.x * 256 + threadIdx.x;
  if (g >= SWZ_TOTAL_GROUPS) return;
  int i = 0;
  #pragma unroll
  for (int t = 1; t < 11; ++t) if (g >= a.gbase[t]) i = t;
  int gl = g - a.gbase[i];
  int KS = a.KS[i], lks = a.lks[i];
  int l = gl & 63, t2 = gl >> 6;
  int ks = t2 & (KS - 1), ct = t2 >> lks;
  const float* src = a.src[i] + (size_t)(ks * 32 + ((l >> 4) << 3)) * 256 + ct * 16 + (l & 15);
  u16 tmp[8];
  #pragma unroll
  for (int j = 0; j < 8; ++j) tmp[j] = f2bf(src[(size_t)j * 256]);
  uint4 pk;
  pk.x = (unsigned)tmp[0] | ((unsigned)tmp[1] << 16);
  pk.y = (unsigned)tmp[2] | ((unsigned)tmp[3] << 16);
  pk.z = (unsigned)tmp[4] | ((unsigned)tmp[5] << 16);
  pk.w = (unsigned)tmp[6] | ((unsigned)tmp[7] << 16);
  *(uint4*)(dst + a.dstoff[i] + (size_t)gl * 8) = pk;
}

// ============================================================
// gating (fp64, unchanged from working round)
// ============================================================
#define GACC(xv, wv)                                \
  l0 = fma((double)(xv), (double)(wv).x, l0);       \
  l1 = fma((double)(xv), (double)(wv).y, l1);       \
  l2 = fma((double)(xv), (double)(wv).z, l2);       \
  l3 = fma((double)(xv), (double)(wv).w, l3);

__global__ __launch_bounds__(256) void k_gate(
    const float* __restrict__ zg, const float* __restrict__ zn,
    const float* __restrict__ gW, const float* __restrict__ gb,
    int* __restrict__ listpos, double* __restrict__ psum,
    int* __restrict__ lists) {
  int row = blockIdx.x * 256 + threadIdx.x;
  int lane = threadIdx.x & 63;
  const float* zgr = zg + (size_t)row * DD;
  const float* znr = zn + (size_t)row * DD;
  double l0 = (double)gb[0], l1 = (double)gb[1], l2 = (double)gb[2], l3 = (double)gb[3];
  for (int i = 0; i < DD; i += 4) {
    float4 a4 = *(const float4*)(zgr + i);
    float4 b4 = *(const float4*)(znr + i);
    float4 wa0 = *(const float4*)(gW + (i + 0) * 4);
    float4 wa1 = *(const float4*)(gW + (i + 1) * 4);
    float4 wa2 = *(const float4*)(gW + (i + 2) * 4);
    float4 wa3 = *(const float4*)(gW + (i + 3) * 4);
    float4 wb0 = *(const float4*)(gW + (DD + i + 0) * 4);
    float4 wb1 = *(const float4*)(gW + (DD + i + 1) * 4);
    float4 wb2 = *(const float4*)(gW + (DD + i + 2) * 4);
    float4 wb3 = *(const float4*)(gW + (DD + i + 3) * 4);
    GACC(a4.x, wa0) GACC(a4.y, wa1) GACC(a4.z, wa2) GACC(a4.w, wa3)
    GACC(b4.x, wb0) GACC(b4.y, wb1) GACC(b4.z, wb2) GACC(b4.w, wb3)
  }
  int e = 0; double lm = l0;
  if (l1 > lm) { lm = l1; e = 1; }
  if (l2 > lm) { lm = l2; e = 2; }
  if (l3 > lm) { lm = l3; e = 3; }
  double s = exp(l0 - lm) + exp(l1 - lm) + exp(l2 - lm) + exp(l3 - lm);
  double p = 1.0 / s;

  #pragma unroll
  for (int ee = 0; ee < NE; ++ee) {
    bool mine = (e == ee);
    unsigned long long mask = __ballot(mine);
    int cnt = __popcll(mask);
    double pv = mine ? p : 0.0;
    #pragma unroll
    for (int off = 32; off; off >>= 1) pv += __shfl_down(pv, off);
    if (cnt) {
      int leader = __ffsll((unsigned long long)mask) - 1;
      int basev = 0;
      if (lane == leader) basev = atomicAdd(&listpos[ee], cnt);
      basev = __shfl(basev, leader);
      if (mine) {
        int rank = __popcll(mask & ((1ull << lane) - 1ull));
        lists[(size_t)ee * BN + basev + rank] = row;
      }
      if (lane == 0) atomicAdd(&psum[ee], pv);
    }
  }
}

__global__ void k_finalize(const int* __restrict__ listpos,
                           const double* __restrict__ psum,
                           float* __restrict__ avg, float* __restrict__ aux_out) {
  if (threadIdx.x == 0) {
    double aux = 0.0;
    for (int ee = 0; ee < NE; ++ee) {
      int c = listpos[ee];
      avg[ee] = (c > 0) ? (float)(psum[ee] / (double)c) : 0.0f;
      double u = (double)c / (double)BN;
      aux += u * u;
    }
    *aux_out = (float)(aux * (double)NE);
  }
}

// ============================================================
// MFMA tile core: wave computes RB row-blocks (16 rows each) x 4 col-tiles
// (cols wave*64 .. wave*64+63). A from LDS bf16 [row][k] (stride elems),
// B from pre-swizzled global bf16.
// ============================================================
template <int KS, int RB>
__device__ __forceinline__ void mfma_gemm(const u16* __restrict__ A, int strideA,
                                          const u16* __restrict__ W,
                                          int wave, int lane, f32x4 acc[RB][4]) {
  int q = lane >> 4, m = lane & 15;
  #pragma unroll
  for (int ks = 0; ks < KS; ++ks) {
    bf16x8 a[RB];
    #pragma unroll
    for (int rb = 0; rb < RB; ++rb)
      a[rb] = *(const bf16x8*)(A + (rb * 16 + m) * strideA + ks * 32 + (q << 3));
    #pragma unroll
    for (int i = 0; i < 4; ++i) {
      int ct = wave * 4 + i;
      bf16x8 b = *(const bf16x8*)(W + (((ct * KS + ks) * 64 + lane) << 3));
      #pragma unroll
      for (int rb = 0; rb < RB; ++rb)
        acc[rb][i] = __builtin_amdgcn_mfma_f32_16x16x32_bf16(a[rb], b, acc[rb][i], 0, 0, 0);
    }
  }
}

// ============================================================
// Expert 0: concat
// ============================================================
__global__ __launch_bounds__(256) void k_concat(
    const float* __restrict__ zg, const float* __restrict__ zn,
    const u16* __restrict__ W1s, const float* __restrict__ b1,
    const u16* __restrict__ W2s, const float* __restrict__ b2,
    const int* __restrict__ listpos, const int* __restrict__ lists,
    const float* __restrict__ avgp, float* __restrict__ out) {
  __shared__ u16 X[32 * 520];
  __shared__ u16 H[32 * 264];
  __shared__ int rl[32];
  int n = listpos[0];
  const int* lst = lists + 0 * (size_t)BN;
  float scale = avgp[0];
  int tid = threadIdx.x, lane = tid & 63, wave = tid >> 6;
  int q = lane >> 4, m = lane & 15;

  for (int tile = blockIdx.x; tile * 32 < n; tile += gridDim.x) {
    int base = tile * 32;
    __syncthreads();
    if (tid < 32) rl[tid] = (base + tid < n) ? lst[base + tid] : -1;
    __syncthreads();
    #pragma unroll
    for (int j = 0; j < 16; ++j) {
      int t = tid + j * 256;            // 4096 float4 chunks
      int row = t >> 7, off = t & 127;  // 128 float4 per 512-row
      int r = rl[row];
      float4 v = make_float4(0.f, 0.f, 0.f, 0.f);
      if (r >= 0)
        v = (off < 64) ? *(const float4*)(zg + (size_t)r * DD + off * 4)
                       : *(const float4*)(zn + (size_t)r * DD + (off - 64) * 4);
      ushort4 pk; pk.x = f2bf(v.x); pk.y = f2bf(v.y); pk.z = f2bf(v.z); pk.w = f2bf(v.w);
      *(ushort4*)(X + row * 520 + off * 4) = pk;
    }
    __syncthreads();
    f32x4 acc[2][4] = {};
    mfma_gemm<16, 2>(X, 520, W1s, wave, lane, acc);
    #pragma unroll
    for (int i = 0; i < 4; ++i) {
      int c = (wave * 4 + i) * 16 + m;
      float bb = b1[c];
      #pragma unroll
      for (int rb = 0; rb < 2; ++rb)
        #pragma unroll
        for (int r = 0; r < 4; ++r)
          H[(rb * 16 + q * 4 + r) * 264 + c] = f2bf(fmaxf(acc[rb][i][r] + bb, 0.f));
    }
    __syncthreads();
    f32x4 acc2[2][4] = {};
    mfma_gemm<8, 2>(H, 264, W2s, wave, lane, acc2);
    #pragma unroll
    for (int i = 0; i < 4; ++i) {
      int c = (wave * 4 + i) * 16 + m;
      float bb = b2[c];
      #pragma unroll
      for (int rb = 0; rb < 2; ++rb)
        #pragma unroll
        for (int r = 0; r < 4; ++r) {
          int row = rl[rb * 16 + q * 4 + r];
          if (row >= 0) out[(size_t)row * DD + c] = (acc2[rb][i][r] + bb) * scale;
        }
    }
  }
}

// ============================================================
// Expert 1: mul
// ============================================================
__global__ __launch_bounds__(256) void k_mul(
    const float* __restrict__ zg, const float* __restrict__ zn,
    const u16* __restrict__ W1s, const float* __restrict__ b1,
    const u16* __restrict__ W2s, const float* __restrict__ b2,
    const int* __restrict__ listpos, const int* __restrict__ lists,
    const float* __restrict__ avgp, float* __restrict__ out) {
  __shared__ u16 X[32 * 264];
  __shared__ u16 H[32 * 264];
  __shared__ int rl[32];
  int n = listpos[1];
  const int* lst = lists + 1 * (size_t)BN;
  float scale = avgp[1];
  int tid = threadIdx.x, lane = tid & 63, wave = tid >> 6;
  int q = lane >> 4, m = lane & 15;

  for (int tile = blockIdx.x; tile * 32 < n; tile += gridDim.x) {
    int base = tile * 32;
    __syncthreads();
    if (tid < 32) rl[tid] = (base + tid < n) ? lst[base + tid] : -1;
    __syncthreads();
    #pragma unroll
    for (int j = 0; j < 8; ++j) {
      int t = tid + j * 256;           // 2048 float4 chunks
      int row = t >> 6, off = t & 63;  // 64 float4 per 256-row
      int r = rl[row];
      float4 v = make_float4(0.f, 0.f, 0.f, 0.f);
      if (r >= 0) {
        float4 g = *(const float4*)(zg + (size_t)r * DD + off * 4);
        float4 h = *(const float4*)(zn + (size_t)r * DD + off * 4);
        v = make_float4(g.x * h.x, g.y * h.y, g.z * h.z, g.w * h.w);
      }
      ushort4 pk; pk.x = f2bf(v.x); pk.y = f2bf(v.y); pk.z = f2bf(v.z); pk.w = f2bf(v.w);
      *(ushort4*)(X + row * 264 + off * 4) = pk;
    }
    __syncthreads();
    f32x4 acc[2][4] = {};
    mfma_gemm<8, 2>(X, 264, W1s, wave, lane, acc);
    #pragma unroll
    for (int i = 0; i < 4; ++i) {
      int c = (wave * 4 + i) * 16 + m;
      float bb = b1[c];
      #pragma unroll
      for (int rb = 0; rb < 2; ++rb)
        #pragma unroll
        for (int r = 0; r < 4; ++r)
          H[(rb * 16 + q * 4 + r) * 264 + c] = f2bf(fmaxf(acc[rb][i][r] + bb, 0.f));
    }
    __syncthreads();
    f32x4 acc2[2][4] = {};
    mfma_gemm<8, 2>(H, 264, W2s, wave, lane, acc2);
    #pragma unroll
    for (int i = 0; i < 4; ++i) {
      int c = (wave * 4 + i) * 16 + m;
      float bb = b2[c];
      #pragma unroll
      for (int rb = 0; rb < 2; ++rb)
        #pragma unroll
        for (int r = 0; r < 4; ++r) {
          int row = rl[rb * 16 + q * 4 + r];
          if (row >= 0) out[(size_t)row * DD + c] = (acc2[rb][i][r] + bb) * scale;
        }
    }
  }
}

// ============================================================
// Expert 3: wsum
// ============================================================
__global__ __launch_bounds__(256) void k_wsum(
    const float* __restrict__ zg, const float* __restrict__ zn,
    const u16* __restrict__ Was, const float* __restrict__ ba,
    const u16* __restrict__ Wos, const float* __restrict__ bo,
    const int* __restrict__ listpos, const int* __restrict__ lists,
    const float* __restrict__ avgp, float* __restrict__ out) {
  __shared__ u16 X[32 * 520];
  __shared__ u16 H[32 * 264];
  __shared__ int rl[32];
  int n = listpos[3];
  const int* lst = lists + 3 * (size_t)BN;
  float scale = avgp[3];
  int tid = threadIdx.x, lane = tid & 63, wave = tid >> 6;
  int q = lane >> 4, m = lane & 15;

  for (int tile = blockIdx.x; tile * 32 < n; tile += gridDim.x) {
    int base = tile * 32;
    __syncthreads();
    if (tid < 32) rl[tid] = (base + tid < n) ? lst[base + tid] : -1;
    __syncthreads();
    #pragma unroll
    for (int j = 0; j < 16; ++j) {
      int t = tid + j * 256;
      int row = t >> 7, off = t & 127;
      int r = rl[row];
      float4 v = make_float4(0.f, 0.f, 0.f, 0.f);
      if (r >= 0)
        v = (off < 64) ? *(const float4*)(zg + (size_t)r * DD + off * 4)
                       : *(const float4*)(zn + (size_t)r * DD + (off - 64) * 4);
      ushort4 pk; pk.x = f2bf(v.x); pk.y = f2bf(v.y); pk.z = f2bf(v.z); pk.w = f2bf(v.w);
      *(ushort4*)(X + row * 520 + off * 4) = pk;
    }
    __syncthreads();
    f32x4 acc[2][4] = {};
    mfma_gemm<16, 2>(X, 520, Was, wave, lane, acc);
    #pragma unroll
    for (int i = 0; i < 4; ++i) {
      int c = (wave * 4 + i) * 16 + m;
      float bb = ba[c];
      #pragma unroll
      for (int rb = 0; rb < 2; ++rb)
        #pragma unroll
        for (int r = 0; r < 4; ++r) {
          int vr = rb * 16 + q * 4 + r;
          float al = 1.f / (1.f + __expf(-(acc[rb][i][r] + bb)));
          float xg = bf2f(X[vr * 520 + c]);
          float xn = bf2f(X[vr * 520 + 256 + c]);
          H[vr * 264 + c] = f2bf(al * xg + (1.f - al) * xn);
        }
    }
    __syncthreads();
    f32x4 acc2[2][4] = {};
    mfma_gemm<8, 2>(H, 264, Wos, wave, lane, acc2);
    #pragma unroll
    for (int i = 0; i < 4; ++i) {
      int c = (wave * 4 + i) * 16 + m;
      float bb = bo[c];
      #pragma unroll
      for (int rb = 0; rb < 2; ++rb)
        #pragma unroll
        for (int r = 0; r < 4; ++r) {
          int row = rl[rb * 16 + q * 4 + r];
          if (row >= 0) out[(size_t)row * DD + c] = (acc2[rb][i][r] + bb) * scale;
        }
    }
  }
}

// ============================================================
// Expert 2: attention. 16 rows/block = 32 vrows (vrow = 2*r + pos).
// ============================================================
__global__ __launch_bounds__(256) void k_attn(
    const float* __restrict__ zg, const float* __restrict__ zn,
    const u16* __restrict__ Wqs, const float* __restrict__ bq,
    const u16* __restrict__ Wks, const float* __restrict__ bk,
    const u16* __restrict__ Wvs, const float* __restrict__ bv,
    const u16* __restrict__ Wos, const float* __restrict__ bo,
    const u16* __restrict__ Wfs, const float* __restrict__ bfc,
    const int* __restrict__ listpos, const int* __restrict__ lists,
    const float* __restrict__ avgp, float* __restrict__ out) {
  __shared__ u16 X[32 * 264];
  __shared__ u16 Qb[32 * 264];   // Q, later O
  __shared__ u16 Kb[32 * 264];
  __shared__ u16 Vb[32 * 264];
  __shared__ u16 Mb[16 * 264];
  __shared__ float SC[256];
  __shared__ float AW[256];
  __shared__ int rl[16];
  int n = listpos[2];
  const int* lst = lists + 2 * (size_t)BN;
  float scale = avgp[2];
  int tid = threadIdx.x, lane = tid & 63, wave = tid >> 6;
  int q = lane >> 4, m = lane & 15;

  for (int tile = blockIdx.x; tile * 16 < n; tile += gridDim.x) {
    int base = tile * 16;
    __syncthreads();
    if (tid < 16) rl[tid] = (base + tid < n) ? lst[base + tid] : -1;
    __syncthreads();
    // stage X: vrow v = 2r+pos; pos0 = zg, pos1 = zn
    #pragma unroll
    for (int j = 0; j < 8; ++j) {
      int t = tid + j * 256;           // 2048 float4 chunks
      int v = t >> 6, off = t & 63;
      int r = rl[v >> 1];
      float4 val = make_float4(0.f, 0.f, 0.f, 0.f);
      if (r >= 0)
        val = (v & 1) ? *(const float4*)(zn + (size_t)r * DD + off * 4)
                      : *(const float4*)(zg + (size_t)r * DD + off * 4);
      ushort4 pk; pk.x = f2bf(val.x); pk.y = f2bf(val.y); pk.z = f2bf(val.z); pk.w = f2bf(val.w);
      *(ushort4*)(X + v * 264 + off * 4) = pk;
    }
    __syncthreads();
    // fused Q,K,V GEMMs (share A-frags)
    {
      f32x4 aq[2][4] = {}, ak[2][4] = {}, av[2][4] = {};
      #pragma unroll
      for (int ks = 0; ks < 8; ++ks) {
        bf16x8 a[2];
        #pragma unroll
        for (int rb = 0; rb < 2; ++rb)
          a[rb] = *(const bf16x8*)(X + (rb * 16 + m) * 264 + ks * 32 + (q << 3));
        #pragma unroll
        for (int i = 0; i < 4; ++i) {
          int ct = wave * 4 + i;
          int fo = ((ct * 8 + ks) * 64 + lane) << 3;
          bf16x8 bqf = *(const bf16x8*)(Wqs + fo);
          bf16x8 bkf = *(const bf16x8*)(Wks + fo);
          bf16x8 bvf = *(const bf16x8*)(Wvs + fo);
          #pragma unroll
          for (int rb = 0; rb < 2; ++rb) {
            aq[rb][i] = __builtin_amdgcn_mfma_f32_16x16x32_bf16(a[rb], bqf, aq[rb][i], 0, 0, 0);
            ak[rb][i] = __builtin_amdgcn_mfma_f32_16x16x32_bf16(a[rb], bkf, ak[rb][i], 0, 0, 0);
            av[rb][i] = __builtin_amdgcn_mfma_f32_16x16x32_bf16(a[rb], bvf, av[rb][i], 0, 0, 0);
          }
        }
      }
      #pragma unroll
      for (int i = 0; i < 4; ++i) {
        int c = (wave * 4 + i) * 16 + m;
        float bbq = bq[c], bbk = bk[c], bbv = bv[c];
        #pragma unroll
        for (int rb = 0; rb < 2; ++rb)
          #pragma unroll
          for (int r = 0; r < 4; ++r) {
            int vr = rb * 16 + q * 4 + r;
            Qb[vr * 264 + c] = f2bf(aq[rb][i][r] + bbq);
            Kb[vr * 264 + c] = f2bf(ak[rb][i][r] + bbk);
            Vb[vr * 264 + c] = f2bf(av[rb][i][r] + bbv);
          }
      }
    }
    __syncthreads();
    // scores: t = r*16 + h*4 + qp*2 + kp
    {
      int kp = tid & 1, qp = (tid >> 1) & 1, h = (tid >> 2) & 3, r = tid >> 4;
      const unsigned int* Qu = (const unsigned int*)Qb;
      const unsigned int* Ku = (const unsigned int*)Kb;
      int qrow = (2 * r + qp) * 132 + h * 32;
      int krow = (2 * r + kp) * 132 + h * 32;
      float s = 0.f;
      #pragma unroll 8
      for (int d = 0; d < 32; ++d) {
        unsigned int qu = Qu[qrow + d], ku = Ku[krow + d];
        s += bf2f((u16)(qu & 0xffff)) * bf2f((u16)(ku & 0xffff))
           + bf2f((u16)(qu >> 16)) * bf2f((u16)(ku >> 16));
      }
      SC[tid] = s * 0.125f;
    }
    __syncthreads();
    {
      float s0 = SC[tid & ~1], s1 = SC[tid | 1];
      float mx = fmaxf(s0, s1);
      float e0 = __expf(s0 - mx), e1 = __expf(s1 - mx);
      float mine = (tid & 1) ? e1 : e0;
      AW[tid] = mine / (e0 + e1);
    }
    __syncthreads();
    // o = a @ v -> overwrite Qb
    {
      const unsigned int* Vu = (const unsigned int*)Vb;
      unsigned int* Ou = (unsigned int*)Qb;
      #pragma unroll
      for (int j = 0; j < 16; ++j) {
        int idx = tid + j * 256;        // vrow*128 + cu
        int v = idx >> 7, cu = idx & 127;
        int r = v >> 1, qp = v & 1, h = cu >> 5;
        int aw = ((r * 4 + h) * 2 + qp) * 2;
        float a0 = AW[aw], a1 = AW[aw + 1];
        unsigned int v0 = Vu[(2 * r) * 132 + cu], v1 = Vu[(2 * r + 1) * 132 + cu];
        float lo = a0 * bf2f((u16)(v0 & 0xffff)) + a1 * bf2f((u16)(v1 & 0xffff));
        float hi = a0 * bf2f((u16)(v0 >> 16)) + a1 * bf2f((u16)(v1 >> 16));
        Ou[v * 132 + cu] = (unsigned int)f2bf(lo) | ((unsigned int)f2bf(hi) << 16);
      }
    }
    __syncthreads();
    // oo = O @ Wo + bo; mean over pos -> Mb[16][264]
    {
      f32x4 acc2[2][4] = {};
      mfma_gemm<8, 2>(Qb, 264, Wos, wave, lane, acc2);
      #pragma unroll
      for (int i = 0; i < 4; ++i) {
        int c = (wave * 4 + i) * 16 + m;
        float bb = bo[c];
        #pragma unroll
        for (int rb = 0; rb < 2; ++rb)
          #pragma unroll
          for (int s = 0; s < 2; ++s) {
            float mv = 0.5f * (acc2[rb][i][2 * s] + acc2[rb][i][2 * s + 1]) + bb;
            Mb[(rb * 8 + q * 2 + s) * 264 + c] = f2bf(mv);
          }
      }
    }
    __syncthreads();
    // out = M @ Wfc + bfc
    {
      f32x4 acc3[1][4] = {};
      mfma_gemm<8, 1>(Mb, 264, Wfs, wave, lane, acc3);
      #pragma unroll
      for (int i = 0; i < 4; ++i) {
        int c = (wave * 4 + i) * 16 + m;
        float bb = bfc[c];
        #pragma unroll
        for (int r = 0; r < 4; ++r) {
          int row = rl[q * 4 + r];
          if (row >= 0) out[(size_t)row * DD + c] = (acc3[0][i][r] + bb) * scale;
        }
      }
    }
  }
}

// ============================================================
// launch
// ============================================================
extern "C" void kernel_launch(void* const* d_in, const int* in_sizes, int n_in,
                              void* d_out, int out_size, void* d_ws, size_t ws_size,
                              hipStream_t stream) {
  const float* zg   = (const float*)d_in[0];
  const float* zn   = (const float*)d_in[1];
  const float* gW   = (const float*)d_in[2];
  const float* gb   = (const float*)d_in[3];
  const float* cW1  = (const float*)d_in[4];
  const float* cb1  = (const float*)d_in[5];
  const float* cW2  = (const float*)d_in[6];
  const float* cb2  = (const float*)d_in[7];
  const float* mW1  = (const float*)d_in[8];
  const float* mb1  = (const float*)d_in[9];
  const float* mW2  = (const float*)d_in[10];
  const float* mb2  = (const float*)d_in[11];
  const float* aWq  = (const float*)d_in[12];
  const float* abq  = (const float*)d_in[13];
  const float* aWk  = (const float*)d_in[14];
  const float* abk  = (const float*)d_in[15];
  const float* aWv  = (const float*)d_in[16];
  const float* abv  = (const float*)d_in[17];
  const float* aWo  = (const float*)d_in[18];
  const float* abo  = (const float*)d_in[19];
  const float* aWfc = (const float*)d_in[20];
  const float* abfc = (const float*)d_in[21];
  const float* wWa  = (const float*)d_in[22];
  const float* wba  = (const float*)d_in[23];
  const float* wWo  = (const float*)d_in[24];
  const float* wbo  = (const float*)d_in[25];
  float* out = (float*)d_out;

  char* ws = (char*)d_ws;
  double* psum  = (double*)ws;
  int* listpos  = (int*)(ws + 32);
  float* avg    = (float*)(ws + 48);
  int* lists    = (int*)(ws + 64);
  u16* wsw      = (u16*)(ws + WS_SWZ_OFF);

  SwzArgs sa;
  const float* srcs[11] = {cW1, cW2, mW1, mW2, aWq, aWk, aWv, aWo, aWfc, wWa, wWo};
  const int   kss[11]  = {16, 8, 8, 8, 8, 8, 8, 8, 8, 16, 8};
  const int   offs[11] = {OFF_CW1, OFF_CW2, OFF_MW1, OFF_MW2, OFF_AWQ, OFF_AWK,
                          OFF_AWV, OFF_AWO, OFF_AWFC, OFF_WWA, OFF_WWO};
  int gb_acc = 0;
  for (int i = 0; i < 11; ++i) {
    sa.src[i] = srcs[i];
    sa.KS[i] = kss[i];
    sa.lks[i] = (kss[i] == 16) ? 4 : 3;
    sa.dstoff[i] = offs[i];
    sa.gbase[i] = gb_acc;
    gb_acc += kss[i] * 1024;
  }

  hipLaunchKernelGGL(k_init, dim3(1), dim3(64), 0, stream, listpos, psum);
  hipLaunchKernelGGL(k_swz, dim3(SWZ_TOTAL_GROUPS / 256), dim3(256), 0, stream, sa, wsw);
  hipLaunchKernelGGL(k_gate, dim3(BN / 256), dim3(256), 0, stream,
                     zg, zn, gW, gb, listpos, psum, lists);
  hipLaunchKernelGGL(k_finalize, dim3(1), dim3(64), 0, stream,
                     listpos, psum, avg, out + (size_t)BN * DD);
  hipLaunchKernelGGL(k_concat, dim3(1024), dim3(256), 0, stream,
                     zg, zn, wsw + OFF_CW1, cb1, wsw + OFF_CW2, cb2, listpos, lists, avg, out);
  hipLaunchKernelGGL(k_mul, dim3(1024), dim3(256), 0, stream,
                     zg, zn, wsw + OFF_MW1, mb1, wsw + OFF_MW2, mb2, listpos, lists, avg, out);
  hipLaunchKernelGGL(k_attn, dim3(2048), dim3(256), 0, stream,
                     zg, zn, wsw + OFF_AWQ, abq, wsw + OFF_AWK, abk, wsw + OFF_AWV, abv,
                     wsw + OFF_AWO, abo, wsw + OFF_AWFC, abfc, listpos, lists, avg, out);
  hipLaunchKernelGGL(k_wsum, dim3(1024), dim3(256), 0, stream,
                     zg, zn, wsw + OFF_WWA, wba, wsw + OFF_WWO, wbo, listpos, lists, avg, out);
}

// Round 3
// 1234.671 us; speedup vs baseline: 2.0811x; 1.2250x over previous
//
#include <hip/hip_runtime.h>
#include <math.h>

#define BN 131072
#define DD 256
#define NE 4

typedef unsigned short u16;
typedef __bf16 bf16x8 __attribute__((ext_vector_type(8)));
typedef float f32x4 __attribute__((ext_vector_type(4)));

__device__ __forceinline__ u16 f2bf(float f) {
  union { float f; unsigned int u; } v; v.f = f;
  unsigned int u = v.u;
  unsigned int r = (u + 0x7FFFu + ((u >> 16) & 1u)) >> 16;
  return (u16)r;
}
__device__ __forceinline__ float bf2f(u16 x) {
  union { unsigned int u; float f; } v; v.u = ((unsigned int)x) << 16; return v.f;
}

// ---------------- workspace layout (d_ws) ----------------
// [0,32)    double psum[4]
// [32,48)   int    listpos[4]
// [48,64)   float  avg[4]
// [64, 64+4*BN*4)  int lists[4][BN]
// [2097216, +1703936) u16 swizzled bf16 weights
#define WS_SWZ_OFF 2097216

#define OFF_CW1  0
#define OFF_CW2  131072
#define OFF_MW1  196608
#define OFF_MW2  262144
#define OFF_AWQ  327680
#define OFF_AWK  393216
#define OFF_AWV  458752
#define OFF_AWO  524288
#define OFF_AWFC 589824
#define OFF_WWA  655360
#define OFF_WWO  786432
#define SWZ_TOTAL_GROUPS 106496   // 851968/8

// ============================================================
// init
// ============================================================
__global__ void k_init(int* __restrict__ listpos, double* __restrict__ psum) {
  int t = threadIdx.x;
  if (t < NE) { listpos[t] = 0; psum[t] = 0.0; }
}

// ============================================================
// weight swizzle: fp32 W[K x 256] -> bf16 in B-fragment order
// ============================================================
struct SwzArgs {
  const float* src[11];
  int KS[11];
  int lks[11];
  int dstoff[11];
  int gbase[11];
};

__global__ __launch_bounds__(256) void k_swz(SwzArgs a, u16* __restrict__ dst) {
  int g = blockIdx.x * 256 + threadIdx.x;
  if (g >= SWZ_TOTAL_GROUPS) return;
  int i = 0;
  #pragma unroll
  for (int t = 1; t < 11; ++t) if (g >= a.gbase[t]) i = t;
  int gl = g - a.gbase[i];
  int KS = a.KS[i], lks = a.lks[i];
  int l = gl & 63, t2 = gl >> 6;
  int ks = t2 & (KS - 1), ct = t2 >> lks;
  const float* src = a.src[i] + (size_t)(ks * 32 + ((l >> 4) << 3)) * 256 + ct * 16 + (l & 15);
  u16 tmp[8];
  #pragma unroll
  for (int j = 0; j < 8; ++j) tmp[j] = f2bf(src[(size_t)j * 256]);
  uint4 pk;
  pk.x = (unsigned)tmp[0] | ((unsigned)tmp[1] << 16);
  pk.y = (unsigned)tmp[2] | ((unsigned)tmp[3] << 16);
  pk.z = (unsigned)tmp[4] | ((unsigned)tmp[5] << 16);
  pk.w = (unsigned)tmp[6] | ((unsigned)tmp[7] << 16);
  *(uint4*)(dst + a.dstoff[i] + (size_t)gl * 8) = pk;
}

// ============================================================
// gating: fp64 accumulation, LDS-staged coalesced reads.
// Block = 256 rows. 16 chunks of 32 floats (zg then zn).
// xs layout transposed: xs[k_local*257 + row] -> conflict-free.
// ============================================================
__global__ __launch_bounds__(256) void k_gate(
    const float* __restrict__ zg, const float* __restrict__ zn,
    const float* __restrict__ gW, const float* __restrict__ gb,
    int* __restrict__ listpos, double* __restrict__ psum,
    int* __restrict__ lists) {
  __shared__ float xs[32 * 257];
  __shared__ double gwd[512 * 4];
  int tid = threadIdx.x, lane = tid & 63;
  int rowbase = blockIdx.x * 256;
  for (int i = tid; i < 2048; i += 256) gwd[i] = (double)gW[i];
  double l0 = (double)gb[0], l1 = (double)gb[1], l2 = (double)gb[2], l3 = (double)gb[3];

  for (int c = 0; c < 16; ++c) {
    const float* src = (c < 8) ? zg : zn;
    int ko = (c & 7) * 32;
    __syncthreads();
    #pragma unroll
    for (int j = 0; j < 8; ++j) {
      int idx = tid + j * 256;       // 2048 float4 slots: 256 rows x 8
      int row = idx >> 3, off = idx & 7;
      float4 v = *(const float4*)(src + (size_t)(rowbase + row) * DD + ko + off * 4);
      xs[(off * 4 + 0) * 257 + row] = v.x;
      xs[(off * 4 + 1) * 257 + row] = v.y;
      xs[(off * 4 + 2) * 257 + row] = v.z;
      xs[(off * 4 + 3) * 257 + row] = v.w;
    }
    __syncthreads();
    const double* gp = gwd + (size_t)(c * 32) * 4;
    #pragma unroll
    for (int i = 0; i < 32; ++i) {
      double x = (double)xs[i * 257 + tid];
      l0 = fma(x, gp[i * 4 + 0], l0);
      l1 = fma(x, gp[i * 4 + 1], l1);
      l2 = fma(x, gp[i * 4 + 2], l2);
      l3 = fma(x, gp[i * 4 + 3], l3);
    }
  }

  int row = rowbase + tid;
  int e = 0; double lm = l0;
  if (l1 > lm) { lm = l1; e = 1; }
  if (l2 > lm) { lm = l2; e = 2; }
  if (l3 > lm) { lm = l3; e = 3; }
  double s = exp(l0 - lm) + exp(l1 - lm) + exp(l2 - lm) + exp(l3 - lm);
  double p = 1.0 / s;

  #pragma unroll
  for (int ee = 0; ee < NE; ++ee) {
    bool mine = (e == ee);
    unsigned long long mask = __ballot(mine);
    int cnt = __popcll(mask);
    double pv = mine ? p : 0.0;
    #pragma unroll
    for (int off = 32; off; off >>= 1) pv += __shfl_down(pv, off);
    if (cnt) {
      int leader = __ffsll((unsigned long long)mask) - 1;
      int basev = 0;
      if (lane == leader) basev = atomicAdd(&listpos[ee], cnt);
      basev = __shfl(basev, leader);
      if (mine) {
        int rank = __popcll(mask & ((1ull << lane) - 1ull));
        lists[(size_t)ee * BN + basev + rank] = row;
      }
      if (lane == 0) atomicAdd(&psum[ee], pv);
    }
  }
}

__global__ void k_finalize(const int* __restrict__ listpos,
                           const double* __restrict__ psum,
                           float* __restrict__ avg, float* __restrict__ aux_out) {
  if (threadIdx.x == 0) {
    double aux = 0.0;
    for (int ee = 0; ee < NE; ++ee) {
      int c = listpos[ee];
      avg[ee] = (c > 0) ? (float)(psum[ee] / (double)c) : 0.0f;
      double u = (double)c / (double)BN;
      aux += u * u;
    }
    *aux_out = (float)(aux * (double)NE);
  }
}

// ============================================================
// MFMA tile core
// ============================================================
template <int KS, int RB>
__device__ __forceinline__ void mfma_gemm(const u16* __restrict__ A, int strideA,
                                          const u16* __restrict__ W,
                                          int wave, int lane, f32x4 acc[RB][4]) {
  int q = lane >> 4, m = lane & 15;
  #pragma unroll
  for (int ks = 0; ks < KS; ++ks) {
    bf16x8 a[RB];
    #pragma unroll
    for (int rb = 0; rb < RB; ++rb)
      a[rb] = *(const bf16x8*)(A + (rb * 16 + m) * strideA + ks * 32 + (q << 3));
    #pragma unroll
    for (int i = 0; i < 4; ++i) {
      int ct = wave * 4 + i;
      bf16x8 b = *(const bf16x8*)(W + (((ct * KS + ks) * 64 + lane) << 3));
      #pragma unroll
      for (int rb = 0; rb < RB; ++rb)
        acc[rb][i] = __builtin_amdgcn_mfma_f32_16x16x32_bf16(a[rb], b, acc[rb][i], 0, 0, 0);
    }
  }
}

// ============================================================
// Expert 0: concat
// ============================================================
__global__ __launch_bounds__(256) void k_concat(
    const float* __restrict__ zg, const float* __restrict__ zn,
    const u16* __restrict__ W1s, const float* __restrict__ b1,
    const u16* __restrict__ W2s, const float* __restrict__ b2,
    const int* __restrict__ listpos, const int* __restrict__ lists,
    const float* __restrict__ avgp, float* __restrict__ out) {
  __shared__ u16 X[32 * 520];
  __shared__ u16 H[32 * 264];
  __shared__ int rl[32];
  int n = listpos[0];
  const int* lst = lists + 0 * (size_t)BN;
  float scale = avgp[0];
  int tid = threadIdx.x, lane = tid & 63, wave = tid >> 6;
  int q = lane >> 4, m = lane & 15;

  for (int tile = blockIdx.x; tile * 32 < n; tile += gridDim.x) {
    int base = tile * 32;
    __syncthreads();
    if (tid < 32) rl[tid] = (base + tid < n) ? lst[base + tid] : -1;
    __syncthreads();
    #pragma unroll
    for (int j = 0; j < 16; ++j) {
      int t = tid + j * 256;
      int row = t >> 7, off = t & 127;
      int r = rl[row];
      float4 v = make_float4(0.f, 0.f, 0.f, 0.f);
      if (r >= 0)
        v = (off < 64) ? *(const float4*)(zg + (size_t)r * DD + off * 4)
                       : *(const float4*)(zn + (size_t)r * DD + (off - 64) * 4);
      ushort4 pk; pk.x = f2bf(v.x); pk.y = f2bf(v.y); pk.z = f2bf(v.z); pk.w = f2bf(v.w);
      *(ushort4*)(X + row * 520 + off * 4) = pk;
    }
    __syncthreads();
    f32x4 acc[2][4] = {};
    mfma_gemm<16, 2>(X, 520, W1s, wave, lane, acc);
    #pragma unroll
    for (int i = 0; i < 4; ++i) {
      int c = (wave * 4 + i) * 16 + m;
      float bb = b1[c];
      #pragma unroll
      for (int rb = 0; rb < 2; ++rb)
        #pragma unroll
        for (int r = 0; r < 4; ++r)
          H[(rb * 16 + q * 4 + r) * 264 + c] = f2bf(fmaxf(acc[rb][i][r] + bb, 0.f));
    }
    __syncthreads();
    f32x4 acc2[2][4] = {};
    mfma_gemm<8, 2>(H, 264, W2s, wave, lane, acc2);
    #pragma unroll
    for (int i = 0; i < 4; ++i) {
      int c = (wave * 4 + i) * 16 + m;
      float bb = b2[c];
      #pragma unroll
      for (int rb = 0; rb < 2; ++rb)
        #pragma unroll
        for (int r = 0; r < 4; ++r) {
          int row = rl[rb * 16 + q * 4 + r];
          if (row >= 0) out[(size_t)row * DD + c] = (acc2[rb][i][r] + bb) * scale;
        }
    }
  }
}

// ============================================================
// Expert 1: mul
// ============================================================
__global__ __launch_bounds__(256) void k_mul(
    const float* __restrict__ zg, const float* __restrict__ zn,
    const u16* __restrict__ W1s, const float* __restrict__ b1,
    const u16* __restrict__ W2s, const float* __restrict__ b2,
    const int* __restrict__ listpos, const int* __restrict__ lists,
    const float* __restrict__ avgp, float* __restrict__ out) {
  __shared__ u16 X[32 * 264];
  __shared__ u16 H[32 * 264];
  __shared__ int rl[32];
  int n = listpos[1];
  const int* lst = lists + 1 * (size_t)BN;
  float scale = avgp[1];
  int tid = threadIdx.x, lane = tid & 63, wave = tid >> 6;
  int q = lane >> 4, m = lane & 15;

  for (int tile = blockIdx.x; tile * 32 < n; tile += gridDim.x) {
    int base = tile * 32;
    __syncthreads();
    if (tid < 32) rl[tid] = (base + tid < n) ? lst[base + tid] : -1;
    __syncthreads();
    #pragma unroll
    for (int j = 0; j < 8; ++j) {
      int t = tid + j * 256;
      int row = t >> 6, off = t & 63;
      int r = rl[row];
      float4 v = make_float4(0.f, 0.f, 0.f, 0.f);
      if (r >= 0) {
        float4 g = *(const float4*)(zg + (size_t)r * DD + off * 4);
        float4 h = *(const float4*)(zn + (size_t)r * DD + off * 4);
        v = make_float4(g.x * h.x, g.y * h.y, g.z * h.z, g.w * h.w);
      }
      ushort4 pk; pk.x = f2bf(v.x); pk.y = f2bf(v.y); pk.z = f2bf(v.z); pk.w = f2bf(v.w);
      *(ushort4*)(X + row * 264 + off * 4) = pk;
    }
    __syncthreads();
    f32x4 acc[2][4] = {};
    mfma_gemm<8, 2>(X, 264, W1s, wave, lane, acc);
    #pragma unroll
    for (int i = 0; i < 4; ++i) {
      int c = (wave * 4 + i) * 16 + m;
      float bb = b1[c];
      #pragma unroll
      for (int rb = 0; rb < 2; ++rb)
        #pragma unroll
        for (int r = 0; r < 4; ++r)
          H[(rb * 16 + q * 4 + r) * 264 + c] = f2bf(fmaxf(acc[rb][i][r] + bb, 0.f));
    }
    __syncthreads();
    f32x4 acc2[2][4] = {};
    mfma_gemm<8, 2>(H, 264, W2s, wave, lane, acc2);
    #pragma unroll
    for (int i = 0; i < 4; ++i) {
      int c = (wave * 4 + i) * 16 + m;
      float bb = b2[c];
      #pragma unroll
      for (int rb = 0; rb < 2; ++rb)
        #pragma unroll
        for (int r = 0; r < 4; ++r) {
          int row = rl[rb * 16 + q * 4 + r];
          if (row >= 0) out[(size_t)row * DD + c] = (acc2[rb][i][r] + bb) * scale;
        }
    }
  }
}

// ============================================================
// Expert 3: wsum
// ============================================================
__global__ __launch_bounds__(256) void k_wsum(
    const float* __restrict__ zg, const float* __restrict__ zn,
    const u16* __restrict__ Was, const float* __restrict__ ba,
    const u16* __restrict__ Wos, const float* __restrict__ bo,
    const int* __restrict__ listpos, const int* __restrict__ lists,
    const float* __restrict__ avgp, float* __restrict__ out) {
  __shared__ u16 X[32 * 520];
  __shared__ u16 H[32 * 264];
  __shared__ int rl[32];
  int n = listpos[3];
  const int* lst = lists + 3 * (size_t)BN;
  float scale = avgp[3];
  int tid = threadIdx.x, lane = tid & 63, wave = tid >> 6;
  int q = lane >> 4, m = lane & 15;

  for (int tile = blockIdx.x; tile * 32 < n; tile += gridDim.x) {
    int base = tile * 32;
    __syncthreads();
    if (tid < 32) rl[tid] = (base + tid < n) ? lst[base + tid] : -1;
    __syncthreads();
    #pragma unroll
    for (int j = 0; j < 16; ++j) {
      int t = tid + j * 256;
      int row = t >> 7, off = t & 127;
      int r = rl[row];
      float4 v = make_float4(0.f, 0.f, 0.f, 0.f);
      if (r >= 0)
        v = (off < 64) ? *(const float4*)(zg + (size_t)r * DD + off * 4)
                       : *(const float4*)(zn + (size_t)r * DD + (off - 64) * 4);
      ushort4 pk; pk.x = f2bf(v.x); pk.y = f2bf(v.y); pk.z = f2bf(v.z); pk.w = f2bf(v.w);
      *(ushort4*)(X + row * 520 + off * 4) = pk;
    }
    __syncthreads();
    f32x4 acc[2][4] = {};
    mfma_gemm<16, 2>(X, 520, Was, wave, lane, acc);
    #pragma unroll
    for (int i = 0; i < 4; ++i) {
      int c = (wave * 4 + i) * 16 + m;
      float bb = ba[c];
      #pragma unroll
      for (int rb = 0; rb < 2; ++rb)
        #pragma unroll
        for (int r = 0; r < 4; ++r) {
          int vr = rb * 16 + q * 4 + r;
          float al = 1.f / (1.f + __expf(-(acc[rb][i][r] + bb)));
          float xg = bf2f(X[vr * 520 + c]);
          float xn = bf2f(X[vr * 520 + 256 + c]);
          H[vr * 264 + c] = f2bf(al * xg + (1.f - al) * xn);
        }
    }
    __syncthreads();
    f32x4 acc2[2][4] = {};
    mfma_gemm<8, 2>(H, 264, Wos, wave, lane, acc2);
    #pragma unroll
    for (int i = 0; i < 4; ++i) {
      int c = (wave * 4 + i) * 16 + m;
      float bb = bo[c];
      #pragma unroll
      for (int rb = 0; rb < 2; ++rb)
        #pragma unroll
        for (int r = 0; r < 4; ++r) {
          int row = rl[rb * 16 + q * 4 + r];
          if (row >= 0) out[(size_t)row * DD + c] = (acc2[rb][i][r] + bb) * scale;
        }
    }
  }
}

// ============================================================
// Expert 2: attention. 16 rows/block = 32 vrows.
// Q, K, V as 3 SEQUENTIAL gemm passes (de-fused: avoids VGPR spill).
// ============================================================
__global__ __launch_bounds__(256) void k_attn(
    const float* __restrict__ zg, const float* __restrict__ zn,
    const u16* __restrict__ Wqs, const float* __restrict__ bq,
    const u16* __restrict__ Wks, const float* __restrict__ bk,
    const u16* __restrict__ Wvs, const float* __restrict__ bv,
    const u16* __restrict__ Wos, const float* __restrict__ bo,
    const u16* __restrict__ Wfs, const float* __restrict__ bfc,
    const int* __restrict__ listpos, const int* __restrict__ lists,
    const float* __restrict__ avgp, float* __restrict__ out) {
  __shared__ u16 X[32 * 264];
  __shared__ u16 Qb[32 * 264];   // Q, later O
  __shared__ u16 Kb[32 * 264];
  __shared__ u16 Vb[32 * 264];
  __shared__ u16 Mb[16 * 264];
  __shared__ float SC[256];
  __shared__ float AW[256];
  __shared__ int rl[16];
  int n = listpos[2];
  const int* lst = lists + 2 * (size_t)BN;
  float scale = avgp[2];
  int tid = threadIdx.x, lane = tid & 63, wave = tid >> 6;
  int q = lane >> 4, m = lane & 15;

  for (int tile = blockIdx.x; tile * 16 < n; tile += gridDim.x) {
    int base = tile * 16;
    __syncthreads();
    if (tid < 16) rl[tid] = (base + tid < n) ? lst[base + tid] : -1;
    __syncthreads();
    // stage X: vrow v = 2r+pos; pos0 = zg, pos1 = zn
    #pragma unroll
    for (int j = 0; j < 8; ++j) {
      int t = tid + j * 256;
      int v = t >> 6, off = t & 63;
      int r = rl[v >> 1];
      float4 val = make_float4(0.f, 0.f, 0.f, 0.f);
      if (r >= 0)
        val = (v & 1) ? *(const float4*)(zn + (size_t)r * DD + off * 4)
                      : *(const float4*)(zg + (size_t)r * DD + off * 4);
      ushort4 pk; pk.x = f2bf(val.x); pk.y = f2bf(val.y); pk.z = f2bf(val.z); pk.w = f2bf(val.w);
      *(ushort4*)(X + v * 264 + off * 4) = pk;
    }
    __syncthreads();
    // ---- Q pass ----
    {
      f32x4 a1[2][4] = {};
      mfma_gemm<8, 2>(X, 264, Wqs, wave, lane, a1);
      #pragma unroll
      for (int i = 0; i < 4; ++i) {
        int c = (wave * 4 + i) * 16 + m;
        float bb = bq[c];
        #pragma unroll
        for (int rb = 0; rb < 2; ++rb)
          #pragma unroll
          for (int r = 0; r < 4; ++r)
            Qb[(rb * 16 + q * 4 + r) * 264 + c] = f2bf(a1[rb][i][r] + bb);
      }
    }
    __syncthreads();
    // ---- K pass ----
    {
      f32x4 a1[2][4] = {};
      mfma_gemm<8, 2>(X, 264, Wks, wave, lane, a1);
      #pragma unroll
      for (int i = 0; i < 4; ++i) {
        int c = (wave * 4 + i) * 16 + m;
        float bb = bk[c];
        #pragma unroll
        for (int rb = 0; rb < 2; ++rb)
          #pragma unroll
          for (int r = 0; r < 4; ++r)
            Kb[(rb * 16 + q * 4 + r) * 264 + c] = f2bf(a1[rb][i][r] + bb);
      }
    }
    __syncthreads();
    // ---- V pass ----
    {
      f32x4 a1[2][4] = {};
      mfma_gemm<8, 2>(X, 264, Wvs, wave, lane, a1);
      #pragma unroll
      for (int i = 0; i < 4; ++i) {
        int c = (wave * 4 + i) * 16 + m;
        float bb = bv[c];
        #pragma unroll
        for (int rb = 0; rb < 2; ++rb)
          #pragma unroll
          for (int r = 0; r < 4; ++r)
            Vb[(rb * 16 + q * 4 + r) * 264 + c] = f2bf(a1[rb][i][r] + bb);
      }
    }
    __syncthreads();
    // scores: t = r*16 + h*4 + qp*2 + kp
    {
      int kp = tid & 1, qp = (tid >> 1) & 1, h = (tid >> 2) & 3, r = tid >> 4;
      const unsigned int* Qu = (const unsigned int*)Qb;
      const unsigned int* Ku = (const unsigned int*)Kb;
      int qrow = (2 * r + qp) * 132 + h * 32;
      int krow = (2 * r + kp) * 132 + h * 32;
      float s = 0.f;
      #pragma unroll 8
      for (int d = 0; d < 32; ++d) {
        unsigned int qu = Qu[qrow + d], ku = Ku[krow + d];
        s += bf2f((u16)(qu & 0xffff)) * bf2f((u16)(ku & 0xffff))
           + bf2f((u16)(qu >> 16)) * bf2f((u16)(ku >> 16));
      }
      SC[tid] = s * 0.125f;
    }
    __syncthreads();
    {
      float s0 = SC[tid & ~1], s1 = SC[tid | 1];
      float mx = fmaxf(s0, s1);
      float e0 = __expf(s0 - mx), e1 = __expf(s1 - mx);
      float mine = (tid & 1) ? e1 : e0;
      AW[tid] = mine / (e0 + e1);
    }
    __syncthreads();
    // o = a @ v -> overwrite Qb
    {
      const unsigned int* Vu = (const unsigned int*)Vb;
      unsigned int* Ou = (unsigned int*)Qb;
      #pragma unroll
      for (int j = 0; j < 16; ++j) {
        int idx = tid + j * 256;
        int v = idx >> 7, cu = idx & 127;
        int r = v >> 1, qp = v & 1, h = cu >> 5;
        int aw = ((r * 4 + h) * 2 + qp) * 2;
        float a0 = AW[aw], a1 = AW[aw + 1];
        unsigned int v0 = Vu[(2 * r) * 132 + cu], v1 = Vu[(2 * r + 1) * 132 + cu];
        float lo = a0 * bf2f((u16)(v0 & 0xffff)) + a1 * bf2f((u16)(v1 & 0xffff));
        float hi = a0 * bf2f((u16)(v0 >> 16)) + a1 * bf2f((u16)(v1 >> 16));
        Ou[v * 132 + cu] = (unsigned int)f2bf(lo) | ((unsigned int)f2bf(hi) << 16);
      }
    }
    __syncthreads();
    // oo = O @ Wo + bo; mean over pos -> Mb[16][264]
    {
      f32x4 acc2[2][4] = {};
      mfma_gemm<8, 2>(Qb, 264, Wos, wave, lane, acc2);
      #pragma unroll
      for (int i = 0; i < 4; ++i) {
        int c = (wave * 4 + i) * 16 + m;
        float bb = bo[c];
        #pragma unroll
        for (int rb = 0; rb < 2; ++rb)
          #pragma unroll
          for (int s = 0; s < 2; ++s) {
            float mv = 0.5f * (acc2[rb][i][2 * s] + acc2[rb][i][2 * s + 1]) + bb;
            Mb[(rb * 8 + q * 2 + s) * 264 + c] = f2bf(mv);
          }
      }
    }
    __syncthreads();
    // out = M @ Wfc + bfc
    {
      f32x4 acc3[1][4] = {};
      mfma_gemm<8, 1>(Mb, 264, Wfs, wave, lane, acc3);
      #pragma unroll
      for (int i = 0; i < 4; ++i) {
        int c = (wave * 4 + i) * 16 + m;
        float bb = bfc[c];
        #pragma unroll
        for (int r = 0; r < 4; ++r) {
          int row = rl[q * 4 + r];
          if (row >= 0) out[(size_t)row * DD + c] = (acc3[0][i][r] + bb) * scale;
        }
      }
    }
  }
}

// ============================================================
// launch
// ============================================================
extern "C" void kernel_launch(void* const* d_in, const int* in_sizes, int n_in,
                              void* d_out, int out_size, void* d_ws, size_t ws_size,
                              hipStream_t stream) {
  const float* zg   = (const float*)d_in[0];
  const float* zn   = (const float*)d_in[1];
  const float* gW   = (const float*)d_in[2];
  const float* gb   = (const float*)d_in[3];
  const float* cW1  = (const float*)d_in[4];
  const float* cb1  = (const float*)d_in[5];
  const float* cW2  = (const float*)d_in[6];
  const float* cb2  = (const float*)d_in[7];
  const float* mW1  = (const float*)d_in[8];
  const float* mb1  = (const float*)d_in[9];
  const float* mW2  = (const float*)d_in[10];
  const float* mb2  = (const float*)d_in[11];
  const float* aWq  = (const float*)d_in[12];
  const float* abq  = (const float*)d_in[13];
  const float* aWk  = (const float*)d_in[14];
  const float* abk  = (const float*)d_in[15];
  const float* aWv  = (const float*)d_in[16];
  const float* abv  = (const float*)d_in[17];
  const float* aWo  = (const float*)d_in[18];
  const float* abo  = (const float*)d_in[19];
  const float* aWfc = (const float*)d_in[20];
  const float* abfc = (const float*)d_in[21];
  const float* wWa  = (const float*)d_in[22];
  const float* wba  = (const float*)d_in[23];
  const float* wWo  = (const float*)d_in[24];
  const float* wbo  = (const float*)d_in[25];
  float* out = (float*)d_out;

  char* ws = (char*)d_ws;
  double* psum  = (double*)ws;
  int* listpos  = (int*)(ws + 32);
  float* avg    = (float*)(ws + 48);
  int* lists    = (int*)(ws + 64);
  u16* wsw      = (u16*)(ws + WS_SWZ_OFF);

  SwzArgs sa;
  const float* srcs[11] = {cW1, cW2, mW1, mW2, aWq, aWk, aWv, aWo, aWfc, wWa, wWo};
  const int   kss[11]  = {16, 8, 8, 8, 8, 8, 8, 8, 8, 16, 8};
  const int   offs[11] = {OFF_CW1, OFF_CW2, OFF_MW1, OFF_MW2, OFF_AWQ, OFF_AWK,
                          OFF_AWV, OFF_AWO, OFF_AWFC, OFF_WWA, OFF_WWO};
  int gb_acc = 0;
  for (int i = 0; i < 11; ++i) {
    sa.src[i] = srcs[i];
    sa.KS[i] = kss[i];
    sa.lks[i] = (kss[i] == 16) ? 4 : 3;
    sa.dstoff[i] = offs[i];
    sa.gbase[i] = gb_acc;
    gb_acc += kss[i] * 1024;
  }

  hipLaunchKernelGGL(k_init, dim3(1), dim3(64), 0, stream, listpos, psum);
  hipLaunchKernelGGL(k_swz, dim3(SWZ_TOTAL_GROUPS / 256), dim3(256), 0, stream, sa, wsw);
  hipLaunchKernelGGL(k_gate, dim3(BN / 256), dim3(256), 0, stream,
                     zg, zn, gW, gb, listpos, psum, lists);
  hipLaunchKernelGGL(k_finalize, dim3(1), dim3(64), 0, stream,
                     listpos, psum, avg, out + (size_t)BN * DD);
  hipLaunchKernelGGL(k_concat, dim3(1024), dim3(256), 0, stream,
                     zg, zn, wsw + OFF_CW1, cb1, wsw + OFF_CW2, cb2, listpos, lists, avg, out);
  hipLaunchKernelGGL(k_mul, dim3(1024), dim3(256), 0, stream,
                     zg, zn, wsw + OFF_MW1, mb1, wsw + OFF_MW2, mb2, listpos, lists, avg, out);
  hipLaunchKernelGGL(k_attn, dim3(2048), dim3(256), 0, stream,
                     zg, zn, wsw + OFF_AWQ, abq, wsw + OFF_AWK, abk, wsw + OFF_AWV, abv,
                     wsw + OFF_AWO, abo, wsw + OFF_AWFC, abfc, listpos, lists, avg, out);
  hipLaunchKernelGGL(k_wsum, dim3(1024), dim3(256), 0, stream,
                     zg, zn, wsw + OFF_WWA, wba, wsw + OFF_WWO, wbo, listpos, lists, avg, out);
}